// Round 5
// baseline (36.961 us; speedup 1.0000x reference)
//
#include <hip/hip_runtime.h>
#include <hip/hip_bf16.h>
#include <float.h>

#define HH 4096
#define WW 4096
#define RROWS 8   // output rows per thread

__global__ __launch_bounds__(256) void nms_kernel(
    const float* __restrict__ rel,
    const float* __restrict__ rep,
    const float* __restrict__ rel_thr_p,
    const float* __restrict__ rep_thr_p,
    int* __restrict__ out)
{
    // XCD-chunked bijective swizzle (nwg = 2048, %8 == 0), then column-major
    // tile walk: each XCD chunk covers 256 vertically-consecutive tiles of one
    // x-column, so the 2 halo rows per tile are same-XCD L2 hits.
    const int bid  = blockIdx.x;          // 0..2047
    const int xcd  = bid & 7;
    const int wgid = xcd * 256 + (bid >> 3);
    const int bx   = wgid >> 9;           // / 512  -> 0..3
    const int by   = wgid & 511;          // % 512

    const int x0    = (bx * 256 + threadIdx.x) * 4;   // 4 px/thread in x
    const int ybase = by * RROWS;
    const int lane  = threadIdx.x & 63;

    const float rel_thr = *rel_thr_p;
    const float rep_thr = *rep_thr_p;
    const float NEG = -FLT_MAX;

    // load rep row yy, return horizontal 3-tap max per pixel; center values in c
    auto loadrow = [&](int yy, float4& c) -> float4 {
        float4 h;
        if (yy < 0 || yy >= HH) {            // wave-uniform (yy uniform per block)
            c = make_float4(NEG, NEG, NEG, NEG);
            return make_float4(NEG, NEG, NEG, NEG);
        }
        const float* row = rep + (size_t)yy * WW;
        const float4 v = *reinterpret_cast<const float4*>(row + x0);
        float left  = __shfl_up(v.w, 1);
        if (lane == 0)  left  = (x0 > 0)      ? row[x0 - 1] : NEG;
        float right = __shfl_down(v.x, 1);
        if (lane == 63) right = (x0 + 4 < WW) ? row[x0 + 4] : NEG;
        c = v;
        h.x = fmaxf(fmaxf(left, v.x), v.y);
        h.y = fmaxf(fmaxf(v.x,  v.y), v.z);
        h.z = fmaxf(fmaxf(v.y,  v.z), v.w);
        h.w = fmaxf(fmaxf(v.z,  v.w), right);
        return h;
    };

    float4 cCur, cNext, cDump;
    float4 hmA = loadrow(ybase - 1, cDump);   // row above
    float4 hmB = loadrow(ybase,     cCur);    // current row

    #pragma unroll
    for (int i = 0; i < RROWS; ++i) {
        const int y = ybase + i;
        float4 hmC = loadrow(y + 1, cNext);   // row below

        // candidate = (rep == 3x3 max) && (rep >= rep_thr)  -- ~3% of pixels
        float m0 = fmaxf(fmaxf(hmA.x, hmB.x), hmC.x);
        float m1 = fmaxf(fmaxf(hmA.y, hmB.y), hmC.y);
        float m2 = fmaxf(fmaxf(hmA.z, hmB.z), hmC.z);
        float m3 = fmaxf(fmaxf(hmA.w, hmB.w), hmC.w);
        const bool k0 = (cCur.x == m0) && (cCur.x >= rep_thr);
        const bool k1 = (cCur.y == m1) && (cCur.y >= rep_thr);
        const bool k2 = (cCur.z == m2) && (cCur.z >= rep_thr);
        const bool k3 = (cCur.w == m3) && (cCur.w >= rep_thr);

        // predicated, NON-TEMPORAL rel load: rel has zero reuse -> stream it,
        // don't evict rep/out-of-window lines from L2/L3.
        float r0 = 0.f, r1 = 0.f, r2 = 0.f, r3 = 0.f;
        if (k0 | k1 | k2 | k3) {
            const float* rp = rel + (size_t)y * WW + x0;
            r0 = __builtin_nontemporal_load(rp + 0);
            r1 = __builtin_nontemporal_load(rp + 1);
            r2 = __builtin_nontemporal_load(rp + 2);
            r3 = __builtin_nontemporal_load(rp + 3);
        }

        int4 o;
        o.x = (k0 && r0 >= rel_thr) ? 1 : 0;
        o.y = (k1 && r1 >= rel_thr) ? 1 : 0;
        o.z = (k2 && r2 >= rel_thr) ? 1 : 0;
        o.w = (k3 && r3 >= rel_thr) ? 1 : 0;

        // NON-TEMPORAL store: out is write-once, never read -> keep it out of
        // L2/L3 so the 64 MB output stream stops evicting the inputs.
        int* op = out + (size_t)y * WW + x0;
        __builtin_nontemporal_store(o.x, op + 0);
        __builtin_nontemporal_store(o.y, op + 1);
        __builtin_nontemporal_store(o.z, op + 2);
        __builtin_nontemporal_store(o.w, op + 3);

        hmA = hmB; hmB = hmC; cCur = cNext;   // roll the 3-row window down
    }
}

extern "C" void kernel_launch(void* const* d_in, const int* in_sizes, int n_in,
                              void* d_out, int out_size, void* d_ws, size_t ws_size,
                              hipStream_t stream)
{
    const float* rel       = (const float*)d_in[0];
    const float* rep       = (const float*)d_in[1];
    const float* rel_thr_p = (const float*)d_in[2];
    const float* rep_thr_p = (const float*)d_in[3];
    int* out = (int*)d_out;

    dim3 block(256, 1, 1);
    dim3 grid(2048, 1, 1);   // 4 x-tiles * 512 y-tiles, swizzled in-kernel
    nms_kernel<<<grid, block, 0, stream>>>(rel, rep, rel_thr_p, rep_thr_p, out);
}

// Round 6
// 34.042 us; speedup vs baseline: 1.0857x; 1.0857x over previous
//
#include <hip/hip_runtime.h>
#include <hip/hip_bf16.h>
#include <float.h>

#define HH 4096
#define WW 4096
#define RROWS 8   // output rows per thread

__global__ __launch_bounds__(256) void nms_kernel(
    const float* __restrict__ rel,
    const float* __restrict__ rep,
    const float* __restrict__ rel_thr_p,
    const float* __restrict__ rep_thr_p,
    int* __restrict__ out)
{
    // XCD-chunked bijective swizzle (nwg = 2048, %8 == 0), then column-major
    // tile walk: halo rows of vertically-adjacent tiles stay same-XCD L2-hot.
    const int bid  = blockIdx.x;          // 0..2047
    const int xcd  = bid & 7;
    const int wgid = xcd * 256 + (bid >> 3);
    const int bx   = wgid >> 9;           // / 512  -> 0..3
    const int by   = wgid & 511;          // % 512

    const int x0    = (bx * 256 + threadIdx.x) * 4;   // 4 px/thread in x
    const int ybase = by * RROWS;
    const int lane  = threadIdx.x & 63;

    const float rel_thr = *rel_thr_p;
    const float rep_thr = *rep_thr_p;
    const float NEG = -FLT_MAX;

    // ---- batch-issue ALL loads first: 10 rep rows + 8 rel rows in flight ----
    float4 v[RROWS + 2];
    #pragma unroll
    for (int r = 0; r < RROWS + 2; ++r) {
        const int yy = ybase + r - 1;
        if (yy >= 0 && yy < HH)    // wave-uniform (only first/last tile rows)
            v[r] = *reinterpret_cast<const float4*>(rep + (size_t)yy * WW + x0);
        else
            v[r] = make_float4(NEG, NEG, NEG, NEG);
    }

    float4 rl[RROWS];
    #pragma unroll
    for (int i = 0; i < RROWS; ++i)
        rl[i] = *reinterpret_cast<const float4*>(rel + (size_t)(ybase + i) * WW + x0);

    // ---- horizontal 3-tap max per row (in-register, shfl for lane edges) ----
    float4 hm[RROWS + 2];
    #pragma unroll
    for (int r = 0; r < RROWS + 2; ++r) {
        const int yy = ybase + r - 1;
        float left  = __shfl_up(v[r].w, 1);
        float right = __shfl_down(v[r].x, 1);
        if (lane == 0)
            left  = (x0 > 0 && yy >= 0 && yy < HH)
                  ? rep[(size_t)yy * WW + x0 - 1] : NEG;
        if (lane == 63)
            right = (x0 + 4 < WW && yy >= 0 && yy < HH)
                  ? rep[(size_t)yy * WW + x0 + 4] : NEG;
        hm[r].x = fmaxf(fmaxf(left,    v[r].x), v[r].y);
        hm[r].y = fmaxf(fmaxf(v[r].x,  v[r].y), v[r].z);
        hm[r].z = fmaxf(fmaxf(v[r].y,  v[r].z), v[r].w);
        hm[r].w = fmaxf(fmaxf(v[r].z,  v[r].w), right);
    }

    // ---- vertical max, compare, store ----
    #pragma unroll
    for (int i = 0; i < RROWS; ++i) {
        const int y = ybase + i;
        const float4 c = v[i + 1];

        const float m0 = fmaxf(fmaxf(hm[i].x, hm[i + 1].x), hm[i + 2].x);
        const float m1 = fmaxf(fmaxf(hm[i].y, hm[i + 1].y), hm[i + 2].y);
        const float m2 = fmaxf(fmaxf(hm[i].z, hm[i + 1].z), hm[i + 2].z);
        const float m3 = fmaxf(fmaxf(hm[i].w, hm[i + 1].w), hm[i + 2].w);

        int4 o;
        o.x = (c.x == m0 && c.x >= rep_thr && rl[i].x >= rel_thr) ? 1 : 0;
        o.y = (c.y == m1 && c.y >= rep_thr && rl[i].y >= rel_thr) ? 1 : 0;
        o.z = (c.z == m2 && c.z >= rep_thr && rl[i].z >= rel_thr) ? 1 : 0;
        o.w = (c.w == m3 && c.w >= rep_thr && rl[i].w >= rel_thr) ? 1 : 0;

        *reinterpret_cast<int4*>(out + (size_t)y * WW + x0) = o;
    }
}

extern "C" void kernel_launch(void* const* d_in, const int* in_sizes, int n_in,
                              void* d_out, int out_size, void* d_ws, size_t ws_size,
                              hipStream_t stream)
{
    const float* rel       = (const float*)d_in[0];
    const float* rep       = (const float*)d_in[1];
    const float* rel_thr_p = (const float*)d_in[2];
    const float* rep_thr_p = (const float*)d_in[3];
    int* out = (int*)d_out;

    dim3 block(256, 1, 1);
    dim3 grid(2048, 1, 1);   // 4 x-tiles * 512 y-tiles, swizzled in-kernel
    nms_kernel<<<grid, block, 0, stream>>>(rel, rep, rel_thr_p, rep_thr_p, out);
}